// Round 5
// baseline (1986.033 us; speedup 1.0000x reference)
//
#include <hip/hip_runtime.h>
#include <hip/hip_fp16.h>
#include <math.h>

// PBELoss: power-flow residual loss.
// residual_i = Sbus_i - V_i * conj( sum_{e: dst(e)=i} Y_e * V_{src(e)} )
// out = [ mean|res|, mean|Re res|, mean|Im res| ]
//
// Fast path: dst-binned two-phase aggregation, 64B-aligned cursor
// reservations (pad slots = zero-records), batched gathers for MLP.
// Fallback (small ws): per-edge packed 64-bit fixed-point atomicAdd.

#define PBE_NT     256
#define PBE_NB     256          // buckets
#define PBE_BSHIFT 13           // 8192 nodes/bucket
#define PBE_BSIZE  8192
#define PBE_TILE   8192
#define PBE_NTB    512          // threads in bin kernel
#define PBE_EPT    (PBE_TILE / PBE_NTB)   // 16

#define PBE_SCALE64       2097152.0f      // 2^21 (fallback)
#define PBE_INV_SCALE64   (1.0f / 2097152.0f)
#define PBE_SCALE_LDS     524288.0f       // 2^19 (bucket accumulate)
#define PBE_INV_SCALE_LDS (1.0f / 524288.0f)

typedef unsigned long long ull;
typedef int iv4 __attribute__((ext_vector_type(4)));
union H2U { __half2 h; unsigned u; };

__device__ __forceinline__ float2 ld_nt_f2(const float2* p) {
    double d = __builtin_nontemporal_load(reinterpret_cast<const double*>(p));
    union { double d; float2 f; } u; u.d = d;
    return u.f;
}
__device__ __forceinline__ int ld_nt_i(const int* p) {
    return __builtin_nontemporal_load(p);
}
__device__ __forceinline__ int2 ld_nt_i2(const int* p) {
    long long v = __builtin_nontemporal_load(reinterpret_cast<const long long*>(p));
    int2 r; r.x = (int)(unsigned)(v & 0xFFFFFFFFll); r.y = (int)(v >> 32);
    return r;
}
__device__ __forceinline__ iv4 ld_nt_iv4(const int* p) {
    return __builtin_nontemporal_load(reinterpret_cast<const iv4*>(p));
}

// ---------------- node prep (vectorized) -------------------------------------
__global__ void pbe_node_prep(const float* __restrict__ pred,
                              const float* __restrict__ target,
                              const int* __restrict__ mask,
                              float* __restrict__ V,
                              float* __restrict__ S,
                              unsigned* __restrict__ Vh,   // may be null
                              int n) {
    int i = blockIdx.x * blockDim.x + threadIdx.x;
    int stride = gridDim.x * blockDim.x;
    for (; i < n; i += stride) {
        int b = 6 * i;
        float2 p0 = ld_nt_f2((const float2*)(pred + b));      // Pd,Qd
        float2 p1 = ld_nt_f2((const float2*)(pred + b + 2));  // Pg,Qg
        float2 p2 = ld_nt_f2((const float2*)(pred + b + 4));  // Vm,Va
        float2 t0 = ld_nt_f2((const float2*)(target + b));
        float2 t1 = ld_nt_f2((const float2*)(target + b + 2));
        float2 t2 = ld_nt_f2((const float2*)(target + b + 4));
        int2 m0 = ld_nt_i2(mask + b);
        int2 m1 = ld_nt_i2(mask + b + 2);
        int2 m2 = ld_nt_i2(mask + b + 4);
        float pd = m0.x ? p0.x : t0.x;
        float qd = m0.y ? p0.y : t0.y;
        float pg = m1.x ? p1.x : t1.x;
        float qg = m1.y ? p1.y : t1.y;
        float vm = m2.x ? p2.x : t2.x;
        float va = m2.y ? p2.y : t2.y;
        float sn, cs;
        sincosf(va, &sn, &cs);
        float vr = vm * cs, vi = vm * sn;
        V[2 * i + 0] = vr;
        V[2 * i + 1] = vi;
        S[2 * i + 0] = pg - pd;
        S[2 * i + 1] = qg - qd;
        if (Vh) { H2U u; u.h = __floats2half2_rn(vr, vi); Vh[i] = u.u; }
    }
}

// ---------------- pass A: global bucket histogram ----------------------------
__global__ void pbe_hist(const int* __restrict__ dst,
                         unsigned* __restrict__ hist_g, int e_total) {
    __shared__ unsigned h[PBE_NB];
    for (int b = threadIdx.x; b < PBE_NB; b += blockDim.x) h[b] = 0;
    __syncthreads();
    int n4 = e_total >> 2;
    int i = blockIdx.x * blockDim.x + threadIdx.x;
    int stride = gridDim.x * blockDim.x;
    for (; i < n4; i += stride) {
        iv4 v = ld_nt_iv4(dst + 4 * i);
        atomicAdd(&h[((unsigned)v[0]) >> PBE_BSHIFT], 1u);
        atomicAdd(&h[((unsigned)v[1]) >> PBE_BSHIFT], 1u);
        atomicAdd(&h[((unsigned)v[2]) >> PBE_BSHIFT], 1u);
        atomicAdd(&h[((unsigned)v[3]) >> PBE_BSHIFT], 1u);
    }
    if (blockIdx.x == 0) {
        for (int t = (n4 << 2) + threadIdx.x; t < e_total; t += blockDim.x)
            atomicAdd(&h[((unsigned)dst[t]) >> PBE_BSHIFT], 1u);
    }
    __syncthreads();
    for (int b = threadIdx.x; b < PBE_NB; b += blockDim.x)
        if (h[b]) atomicAdd(&hist_g[b], h[b]);
}

// ---------------- pass B: capacity prefix (A-aligned bases) ------------------
__global__ void pbe_prefix(const unsigned* __restrict__ hist_g,
                           unsigned* __restrict__ base,
                           unsigned* __restrict__ cursor,
                           int A, int n_tiles) {
    __shared__ unsigned tmp[PBE_NB];
    int t = threadIdx.x;
    unsigned c = hist_g[t];
    unsigned Au = (unsigned)A;
    unsigned cap = 0;
    if (c) {
        cap = c + (Au - 1u) * (unsigned)n_tiles;   // worst-case per-tile padding
        cap = (cap + Au - 1u) & ~(Au - 1u);
    }
    tmp[t] = cap;
    __syncthreads();
    for (int o = 1; o < PBE_NB; o <<= 1) {
        unsigned u = (t >= o) ? tmp[t - o] : 0u;
        __syncthreads();
        tmp[t] += u;
        __syncthreads();
    }
    unsigned excl = tmp[t] - cap;
    base[t] = excl;
    cursor[t] = excl;
}

// ---------------- pass C: bin edges (aligned reservations, batched gathers) --
__global__ void __launch_bounds__(PBE_NTB)
pbe_bin(const float2* __restrict__ Y,
        const int* __restrict__ src,
        const int* __restrict__ dst,
        const unsigned* __restrict__ Vh,
        ull* __restrict__ rec,
        unsigned* __restrict__ cursor,
        int A, int e_total) {
    __shared__ unsigned hist[PBE_NB];
    __shared__ unsigned lcur[PBE_NB];
    __shared__ unsigned goff[PBE_NB];
    const int tile0 = blockIdx.x * PBE_TILE;
    const int tid = threadIdx.x;
    for (int b = tid; b < PBE_NB; b += PBE_NTB) { hist[b] = 0; lcur[b] = 0; }
    __syncthreads();

    // phase 1: batched dst loads + LDS histogram
    int d[PBE_EPT];
    #pragma unroll
    for (int k = 0; k < PBE_EPT; ++k) {
        int i = tile0 + k * PBE_NTB + tid;
        d[k] = (i < e_total) ? ld_nt_i(dst + i) : -1;
    }
    #pragma unroll
    for (int k = 0; k < PBE_EPT; ++k)
        if (d[k] >= 0) atomicAdd(&hist[((unsigned)d[k]) >> PBE_BSHIFT], 1u);
    __syncthreads();

    // phase 2: one aligned cursor reservation per active bucket; zero-fill pads
    if (tid < PBE_NB) {
        unsigned c = hist[tid];
        if (c) {
            unsigned Au = (unsigned)A;
            unsigned ru = (c + Au - 1u) & ~(Au - 1u);
            unsigned g = atomicAdd(&cursor[tid], ru);
            goff[tid] = g;
            for (unsigned p = c; p < ru; ++p)
                rec[g + p] = 0ull;                 // pad: msg=0 -> accumulates 0
        }
    }
    __syncthreads();

    // phase 3: two batches of 8 edges -> 8 gathers in flight per thread
    #pragma unroll
    for (int h = 0; h < PBE_EPT / 8; ++h) {
        int s8[8]; unsigned uv[8]; float2 y8[8];
        #pragma unroll
        for (int j = 0; j < 8; ++j) {
            int k = h * 8 + j;
            int i = tile0 + k * PBE_NTB + tid;
            s8[j] = (d[k] >= 0) ? ld_nt_i(src + i) : 0;
        }
        #pragma unroll
        for (int j = 0; j < 8; ++j) uv[j] = Vh[s8[j]];   // random 4B gathers
        #pragma unroll
        for (int j = 0; j < 8; ++j) {
            int k = h * 8 + j;
            int i = tile0 + k * PBE_NTB + tid;
            y8[j] = (d[k] >= 0) ? ld_nt_f2(Y + i) : make_float2(0.f, 0.f);
        }
        #pragma unroll
        for (int j = 0; j < 8; ++j) {
            int k = h * 8 + j;
            if (d[k] < 0) continue;
            unsigned b = ((unsigned)d[k]) >> PBE_BSHIFT;
            unsigned r = atomicAdd(&lcur[b], 1u);
            H2U uvh; uvh.u = uv[j];
            float vr = __low2float(uvh.h), vi = __high2float(uvh.h);
            float mr = y8[j].x * vr - y8[j].y * vi;
            float mi = y8[j].x * vi + y8[j].y * vr;
            H2U um; um.h = __floats2half2_rn(mr, mi);
            ull packed = ((ull)(unsigned)(d[k] & (PBE_BSIZE - 1)) << 32) | um.u;
            __builtin_nontemporal_store(packed, &rec[goff[b] + r]);
        }
    }
}

// ---------------- pass D: per-bucket exact accumulation ----------------------
__global__ void __launch_bounds__(512)
pbe_bucket_acc(const ull* __restrict__ rec,
               const unsigned* __restrict__ base,
               const unsigned* __restrict__ cursor,  // post-bin = end of used
               float* __restrict__ I, int n_nodes) {
    extern __shared__ int lds[];
    int* accR = lds;
    int* accI = lds + PBE_BSIZE;
    for (int j = threadIdx.x; j < PBE_BSIZE; j += 512) { accR[j] = 0; accI[j] = 0; }
    __syncthreads();
    const int b = blockIdx.x;
    const unsigned lo = base[b], hi = cursor[b];
    for (unsigned t = lo + threadIdx.x; t < hi; t += 512) {
        ull p = __builtin_nontemporal_load(rec + t);
        H2U um; um.u = (unsigned)p;
        unsigned dl = (unsigned)(p >> 32);
        int qr = __float2int_rn(__low2float(um.h) * PBE_SCALE_LDS);
        int qi = __float2int_rn(__high2float(um.h) * PBE_SCALE_LDS);
        if (qr) atomicAdd(&accR[dl], qr);
        if (qi) atomicAdd(&accI[dl], qi);
    }
    __syncthreads();
    const int node0 = b << PBE_BSHIFT;
    for (int j = threadIdx.x; j < PBE_BSIZE; j += 512) {
        int n = node0 + j;
        if (n < n_nodes) {
            I[2 * n + 0] = accR[j] * PBE_INV_SCALE_LDS;
            I[2 * n + 1] = accI[j] * PBE_INV_SCALE_LDS;
        }
    }
}

// ---------------- fallback: per-edge packed 64-bit atomic --------------------
__device__ __forceinline__ void pbe_edge_one(float2 gb, int s, int d,
                                             const float2* __restrict__ V,
                                             ull* __restrict__ Iq) {
    float2 v = V[s];
    float mr = gb.x * v.x - gb.y * v.y;
    float mi = gb.x * v.y + gb.y * v.x;
    int qr = __float2int_rn(mr * PBE_SCALE64);
    int qi = __float2int_rn(mi * PBE_SCALE64);
    ull pack = ((ull)(unsigned)qr << 32) + (ull)(long long)qi;
    atomicAdd(&Iq[d], pack);
}

__global__ void __launch_bounds__(PBE_NT)
pbe_edge_scatter(const float2* __restrict__ edge_attr,
                 const int* __restrict__ src,
                 const int* __restrict__ dst,
                 const float2* __restrict__ V,
                 ull* __restrict__ Iq,
                 int e_total) {
    int i = blockIdx.x * blockDim.x + threadIdx.x;
    const int stride = gridDim.x * blockDim.x;
    for (; i + 3 * stride < e_total; i += 4 * stride) {
        int ia = i, ib = i + stride, ic = i + 2 * stride, id = i + 3 * stride;
        float2 ga = ld_nt_f2(edge_attr + ia);
        float2 gb = ld_nt_f2(edge_attr + ib);
        float2 gc = ld_nt_f2(edge_attr + ic);
        float2 gd = ld_nt_f2(edge_attr + id);
        int sa = ld_nt_i(src + ia), sb = ld_nt_i(src + ib);
        int sc = ld_nt_i(src + ic), sd = ld_nt_i(src + id);
        int da = ld_nt_i(dst + ia), db = ld_nt_i(dst + ib);
        int dc = ld_nt_i(dst + ic), dd = ld_nt_i(dst + id);
        pbe_edge_one(ga, sa, da, V, Iq);
        pbe_edge_one(gb, sb, db, V, Iq);
        pbe_edge_one(gc, sc, dc, V, Iq);
        pbe_edge_one(gd, sd, dd, V, Iq);
    }
    for (; i < e_total; i += stride) {
        float2 g = ld_nt_f2(edge_attr + i);
        pbe_edge_one(g, ld_nt_i(src + i), ld_nt_i(dst + i), V, Iq);
    }
}

__global__ void pbe_unpack_iq(ull* __restrict__ Iq, float* __restrict__ I, int n) {
    int i = blockIdx.x * blockDim.x + threadIdx.x;
    int stride = gridDim.x * blockDim.x;
    for (; i < n; i += stride) {
        long long q = (long long)Iq[i];
        int lo = (int)(unsigned)(q & 0xFFFFFFFFll);
        int hi = (int)((q - (long long)lo) >> 32);
        float re = hi * PBE_INV_SCALE64;
        float im = lo * PBE_INV_SCALE64;
        I[2 * i + 0] = re;
        I[2 * i + 1] = im;
    }
}

// ---------------- residual + reduction ---------------------------------------
__global__ void pbe_reduce(const float* __restrict__ V,
                           const float* __restrict__ S,
                           const float* __restrict__ I,
                           float* __restrict__ sums, int n) {
    float a0 = 0.f, a1 = 0.f, a2 = 0.f;
    int i = blockIdx.x * blockDim.x + threadIdx.x;
    int stride = gridDim.x * blockDim.x;
    for (; i < n; i += stride) {
        float2 v  = reinterpret_cast<const float2*>(V)[i];
        float2 sb = reinterpret_cast<const float2*>(S)[i];
        float2 cc = reinterpret_cast<const float2*>(I)[i];
        float rr = sb.x - (v.x * cc.x + v.y * cc.y);
        float ri = sb.y - (v.y * cc.x - v.x * cc.y);
        a0 += sqrtf(rr * rr + ri * ri);
        a1 += fabsf(rr);
        a2 += fabsf(ri);
    }
    #pragma unroll
    for (int off = 32; off > 0; off >>= 1) {
        a0 += __shfl_down(a0, off);
        a1 += __shfl_down(a1, off);
        a2 += __shfl_down(a2, off);
    }
    __shared__ float sm[3][PBE_NT / 64];
    int wid  = threadIdx.x >> 6;
    int lane = threadIdx.x & 63;
    if (lane == 0) { sm[0][wid] = a0; sm[1][wid] = a1; sm[2][wid] = a2; }
    __syncthreads();
    if (threadIdx.x == 0) {
        float t0 = 0.f, t1 = 0.f, t2 = 0.f;
        #pragma unroll
        for (int w = 0; w < PBE_NT / 64; ++w) {
            t0 += sm[0][w]; t1 += sm[1][w]; t2 += sm[2][w];
        }
        atomicAdd(&sums[0], t0);
        atomicAdd(&sums[1], t1);
        atomicAdd(&sums[2], t2);
    }
}

__global__ void pbe_finalize(const float* __restrict__ sums,
                             float* __restrict__ out, float inv_n) {
    int t = threadIdx.x;
    if (t < 3) out[t] = sums[t] * inv_n;
}

static inline size_t align256(size_t x) { return (x + 255) & ~(size_t)255; }

extern "C" void kernel_launch(void* const* d_in, const int* in_sizes, int n_in,
                              void* d_out, int out_size, void* d_ws, size_t ws_size,
                              hipStream_t stream) {
    const float* pred      = (const float*)d_in[0];
    const float* target    = (const float*)d_in[1];
    const float* edge_attr = (const float*)d_in[2];
    const int*   edge_idx  = (const int*)d_in[3]; // [2, E] int32
    const int*   mask      = (const int*)d_in[4]; // bool -> int32

    const int n_nodes = in_sizes[0] / 6;
    const int n_edges = in_sizes[2] / 2;
    const int* src = edge_idx;
    const int* dst = edge_idx + n_edges;

    const int NBa     = (n_nodes + PBE_BSIZE - 1) / PBE_BSIZE;  // active buckets
    const int n_tiles = (n_edges + PBE_TILE - 1) / PBE_TILE;

    char* w = (char*)d_ws;

    // Pick largest reservation alignment A in {8,4,1} that fits ws.
    int A = 0;
    size_t oV = 0, oS = 0, oI = 0, oVh = 0, oRec = 0, oHist = 0, oBase = 0,
           oCur = 0, oSums = 0, need = 0;
    const int cand[3] = {8, 4, 1};
    for (int ci = 0; ci < 3 && A == 0; ++ci) {
        int a = cand[ci];
        size_t rec_slots = (size_t)n_edges +
            (size_t)PBE_NB * ((size_t)(a - 1) * (size_t)(n_tiles + 1) + (size_t)a);
        oV    = 0;
        oS    = align256(oV + (size_t)2 * n_nodes * 4);
        oI    = align256(oS + (size_t)2 * n_nodes * 4);
        oVh   = align256(oI + (size_t)2 * n_nodes * 4);
        oRec  = align256(oVh + (size_t)n_nodes * 4);
        oHist = align256(oRec + rec_slots * 8);
        oBase = align256(oHist + PBE_NB * 4);
        oCur  = align256(oBase + PBE_NB * 4);
        oSums = align256(oCur + PBE_NB * 4);
        need  = oSums + 3 * 4;
        if (ws_size >= need && NBa <= PBE_NB) A = a;
    }

    float*    V      = (float*)(w + oV);
    float*    S      = (float*)(w + oS);
    float*    I      = (float*)(w + oI);
    unsigned* Vh     = (unsigned*)(w + oVh);
    ull*      rec    = (ull*)(w + oRec);
    unsigned* hist_g = (unsigned*)(w + oHist);
    unsigned* base   = (unsigned*)(w + oBase);
    unsigned* cursor = (unsigned*)(w + oCur);
    float*    sums   = (float*)(w + oSums);

    const int T = PBE_NT;
    int grid_nodes = (n_nodes + T - 1) / T;
    if (grid_nodes > 4096) grid_nodes = 4096;

    if (A > 0) {
        hipMemsetAsync(hist_g, 0, PBE_NB * sizeof(unsigned), stream);
        hipMemsetAsync(sums, 0, 3 * sizeof(float), stream);

        pbe_node_prep<<<grid_nodes, T, 0, stream>>>(pred, target, mask, V, S, Vh, n_nodes);
        pbe_hist<<<1024, T, 0, stream>>>(dst, hist_g, n_edges);
        pbe_prefix<<<1, PBE_NB, 0, stream>>>(hist_g, base, cursor, A, n_tiles);
        pbe_bin<<<n_tiles, PBE_NTB, 0, stream>>>((const float2*)edge_attr, src, dst,
                                                 Vh, rec, cursor, A, n_edges);
        pbe_bucket_acc<<<NBa, 512, 2 * PBE_BSIZE * sizeof(int), stream>>>(
            rec, base, cursor, I, n_nodes);
        pbe_reduce<<<grid_nodes, T, 0, stream>>>(V, S, I, sums, n_nodes);
        pbe_finalize<<<1, 64, 0, stream>>>(sums, (float*)d_out, 1.0f / (float)n_nodes);
    } else {
        // fallback: packed 64-bit fixed-point atomics (round-3 scheme)
        ull* Iq = (ull*)(w + oI);
        float* sums_fb = (float*)(w + oVh);
        hipMemsetAsync(Iq, 0, (size_t)n_nodes * 8, stream);
        hipMemsetAsync(sums_fb, 0, 3 * sizeof(float), stream);
        int grid_edges = (n_edges + T - 1) / T;
        if (grid_edges > 8192) grid_edges = 8192;
        pbe_node_prep<<<grid_nodes, T, 0, stream>>>(pred, target, mask, V, S,
                                                    (unsigned*)nullptr, n_nodes);
        pbe_edge_scatter<<<grid_edges, T, 0, stream>>>(
            (const float2*)edge_attr, src, dst, (const float2*)V, Iq, n_edges);
        pbe_unpack_iq<<<grid_nodes, T, 0, stream>>>(Iq, (float*)(w + oI), n_nodes);
        pbe_reduce<<<grid_nodes, T, 0, stream>>>(V, S, (float*)(w + oI), sums_fb, n_nodes);
        pbe_finalize<<<1, 64, 0, stream>>>(sums_fb, (float*)d_out, 1.0f / (float)n_nodes);
    }
}

// Round 6
// 832.730 us; speedup vs baseline: 2.3850x; 2.3850x over previous
//
#include <hip/hip_runtime.h>
#include <hip/hip_fp16.h>
#include <math.h>

// PBELoss: power-flow residual loss.
// residual_i = Sbus_i - V_i * conj( sum_{e: dst(e)=i} Y_e * V_{src(e)} )
// out = [ mean|res|, mean|Re res|, mean|Im res| ]
//
// Fast path: dst-binned aggregation. Bin pass stages each 4096-edge tile's
// records in LDS sorted by bucket, then copies out wave-coalesced (exact-size
// reservations -> rec capacity == E, no padding). Per-bucket accumulate is
// exact int32 fixed-point in LDS (deterministic).
// Fallback (small ws): per-edge packed 64-bit fixed-point atomicAdd.

#define PBE_NT     256
#define PBE_NB     512          // buckets
#define PBE_BSHIFT 12           // 4096 nodes/bucket
#define PBE_BSIZE  4096
#define PBE_TILE   4096
#define PBE_NTB    512          // threads in bin kernel
#define PBE_EPT    (PBE_TILE / PBE_NTB)   // 8

#define PBE_SCALE64       2097152.0f      // 2^21 (fallback)
#define PBE_INV_SCALE64   (1.0f / 2097152.0f)
#define PBE_SCALE_LDS     524288.0f       // 2^19 (bucket accumulate)
#define PBE_INV_SCALE_LDS (1.0f / 524288.0f)

typedef unsigned long long ull;
typedef int iv4 __attribute__((ext_vector_type(4)));
union H2U { __half2 h; unsigned u; };

__device__ __forceinline__ float2 ld_nt_f2(const float2* p) {
    double d = __builtin_nontemporal_load(reinterpret_cast<const double*>(p));
    union { double d; float2 f; } u; u.d = d;
    return u.f;
}
__device__ __forceinline__ int ld_nt_i(const int* p) {
    return __builtin_nontemporal_load(p);
}
__device__ __forceinline__ int2 ld_nt_i2(const int* p) {
    long long v = __builtin_nontemporal_load(reinterpret_cast<const long long*>(p));
    int2 r; r.x = (int)(unsigned)(v & 0xFFFFFFFFll); r.y = (int)(v >> 32);
    return r;
}
__device__ __forceinline__ iv4 ld_nt_iv4(const int* p) {
    return __builtin_nontemporal_load(reinterpret_cast<const iv4*>(p));
}

// ---------------- node prep (vectorized) -------------------------------------
__global__ void pbe_node_prep(const float* __restrict__ pred,
                              const float* __restrict__ target,
                              const int* __restrict__ mask,
                              float* __restrict__ V,
                              float* __restrict__ S,
                              unsigned* __restrict__ Vh,   // may be null
                              int n) {
    int i = blockIdx.x * blockDim.x + threadIdx.x;
    int stride = gridDim.x * blockDim.x;
    for (; i < n; i += stride) {
        int b = 6 * i;
        float2 p0 = ld_nt_f2((const float2*)(pred + b));
        float2 p1 = ld_nt_f2((const float2*)(pred + b + 2));
        float2 p2 = ld_nt_f2((const float2*)(pred + b + 4));
        float2 t0 = ld_nt_f2((const float2*)(target + b));
        float2 t1 = ld_nt_f2((const float2*)(target + b + 2));
        float2 t2 = ld_nt_f2((const float2*)(target + b + 4));
        int2 m0 = ld_nt_i2(mask + b);
        int2 m1 = ld_nt_i2(mask + b + 2);
        int2 m2 = ld_nt_i2(mask + b + 4);
        float pd = m0.x ? p0.x : t0.x;
        float qd = m0.y ? p0.y : t0.y;
        float pg = m1.x ? p1.x : t1.x;
        float qg = m1.y ? p1.y : t1.y;
        float vm = m2.x ? p2.x : t2.x;
        float va = m2.y ? p2.y : t2.y;
        float sn, cs;
        sincosf(va, &sn, &cs);
        float vr = vm * cs, vi = vm * sn;
        V[2 * i + 0] = vr;
        V[2 * i + 1] = vi;
        S[2 * i + 0] = pg - pd;
        S[2 * i + 1] = qg - qd;
        if (Vh) { H2U u; u.h = __floats2half2_rn(vr, vi); Vh[i] = u.u; }
    }
}

// ---------------- pass A: global bucket histogram ----------------------------
__global__ void pbe_hist(const int* __restrict__ dst,
                         unsigned* __restrict__ hist_g, int e_total) {
    __shared__ unsigned h[PBE_NB];
    for (int b = threadIdx.x; b < PBE_NB; b += blockDim.x) h[b] = 0;
    __syncthreads();
    int n4 = e_total >> 2;
    int i = blockIdx.x * blockDim.x + threadIdx.x;
    int stride = gridDim.x * blockDim.x;
    for (; i < n4; i += stride) {
        iv4 v = ld_nt_iv4(dst + 4 * i);
        atomicAdd(&h[((unsigned)v[0]) >> PBE_BSHIFT], 1u);
        atomicAdd(&h[((unsigned)v[1]) >> PBE_BSHIFT], 1u);
        atomicAdd(&h[((unsigned)v[2]) >> PBE_BSHIFT], 1u);
        atomicAdd(&h[((unsigned)v[3]) >> PBE_BSHIFT], 1u);
    }
    if (blockIdx.x == 0) {
        for (int t = (n4 << 2) + threadIdx.x; t < e_total; t += blockDim.x)
            atomicAdd(&h[((unsigned)dst[t]) >> PBE_BSHIFT], 1u);
    }
    __syncthreads();
    for (int b = threadIdx.x; b < PBE_NB; b += blockDim.x)
        if (h[b]) atomicAdd(&hist_g[b], h[b]);
}

// ---------------- pass B: exclusive prefix -> base, cursor -------------------
__global__ void pbe_prefix(const unsigned* __restrict__ hist_g,
                           unsigned* __restrict__ base,
                           unsigned* __restrict__ cursor) {
    __shared__ unsigned tmp[PBE_NB];
    int t = threadIdx.x;
    unsigned mine = hist_g[t];
    tmp[t] = mine;
    __syncthreads();
    for (int o = 1; o < PBE_NB; o <<= 1) {
        unsigned u = (t >= o) ? tmp[t - o] : 0u;
        __syncthreads();
        tmp[t] += u;
        __syncthreads();
    }
    unsigned excl = tmp[t] - mine;
    base[t] = excl;
    cursor[t] = excl;
}

// ---------------- pass C: bin via LDS staging + coalesced copy-out -----------
__global__ void __launch_bounds__(PBE_NTB)
pbe_bin(const float2* __restrict__ Y,
        const int* __restrict__ src,
        const int* __restrict__ dst,
        const unsigned* __restrict__ Vh,
        ull* __restrict__ rec,
        unsigned* __restrict__ cursor,
        int e_total) {
    __shared__ unsigned hist[PBE_NB];
    __shared__ unsigned lbase[PBE_NB];    // per-tile exclusive prefix (LDS pos)
    __shared__ unsigned delta[PBE_NB];    // global_off - lbase
    __shared__ unsigned lcur[PBE_NB];
    __shared__ ull recs[PBE_TILE];        // 32 KB staged records
    __shared__ unsigned short bkt[PBE_TILE]; // 8 KB bucket id per staged record

    const int tile0 = blockIdx.x * PBE_TILE;
    const int tid = threadIdx.x;
    hist[tid] = 0; lcur[tid] = 0;         // PBE_NTB == PBE_NB == 512
    __syncthreads();

    // phase 1: dst loads + tile histogram
    int d[PBE_EPT];
    #pragma unroll
    for (int k = 0; k < PBE_EPT; ++k) {
        int i = tile0 + k * PBE_NTB + tid;
        d[k] = (i < e_total) ? ld_nt_i(dst + i) : -1;
    }
    #pragma unroll
    for (int k = 0; k < PBE_EPT; ++k)
        if (d[k] >= 0) atomicAdd(&hist[((unsigned)d[k]) >> PBE_BSHIFT], 1u);
    __syncthreads();

    // phase 2: LDS prefix (Hillis-Steele over 512) + exact global reservation
    {
        unsigned mine = hist[tid];
        lbase[tid] = mine;
        __syncthreads();
        #pragma unroll
        for (int o = 1; o < PBE_NB; o <<= 1) {
            unsigned u = (tid >= o) ? lbase[tid - o] : 0u;
            __syncthreads();
            lbase[tid] += u;
            __syncthreads();
        }
        unsigned incl = lbase[tid];
        unsigned excl = incl - mine;
        __syncthreads();
        lbase[tid] = excl;
        unsigned g = mine ? atomicAdd(&cursor[tid], mine) : 0u;
        delta[tid] = g - excl;            // unsigned wrap is fine
    }
    __syncthreads();

    // phase 3: batched gathers -> scatter records into LDS by bucket rank
    #pragma unroll
    for (int h = 0; h < PBE_EPT / 8; ++h) {
        int s8[8]; unsigned uv[8]; float2 y8[8];
        #pragma unroll
        for (int j = 0; j < 8; ++j) {
            int k = h * 8 + j;
            int i = tile0 + k * PBE_NTB + tid;
            s8[j] = (d[k] >= 0) ? ld_nt_i(src + i) : 0;
        }
        #pragma unroll
        for (int j = 0; j < 8; ++j) uv[j] = Vh[s8[j]];   // random 4B gathers
        #pragma unroll
        for (int j = 0; j < 8; ++j) {
            int k = h * 8 + j;
            int i = tile0 + k * PBE_NTB + tid;
            y8[j] = (d[k] >= 0) ? ld_nt_f2(Y + i) : make_float2(0.f, 0.f);
        }
        #pragma unroll
        for (int j = 0; j < 8; ++j) {
            int k = h * 8 + j;
            if (d[k] < 0) continue;
            unsigned b = ((unsigned)d[k]) >> PBE_BSHIFT;
            unsigned pos = lbase[b] + atomicAdd(&lcur[b], 1u);
            H2U uvh; uvh.u = uv[j];
            float vr = __low2float(uvh.h), vi = __high2float(uvh.h);
            float mr = y8[j].x * vr - y8[j].y * vi;
            float mi = y8[j].x * vi + y8[j].y * vr;
            H2U um; um.h = __floats2half2_rn(mr, mi);
            recs[pos] = ((ull)(unsigned)(d[k] & (PBE_BSIZE - 1)) << 32) | um.u;
            bkt[pos] = (unsigned short)b;
        }
    }
    __syncthreads();

    // phase 4: coalesced copy-out (consecutive lanes -> consecutive addresses
    // within each bucket run). NT store keeps rec lines out of L2.
    unsigned staged = lbase[PBE_NB - 1] + hist[PBE_NB - 1];
    for (unsigned j = tid; j < staged; j += PBE_NTB) {
        unsigned b = bkt[j];
        __builtin_nontemporal_store(recs[j], &rec[j + delta[b]]);
    }
}

// ---------------- pass D: per-bucket exact accumulation ----------------------
__global__ void __launch_bounds__(512)
pbe_bucket_acc(const ull* __restrict__ rec,
               const unsigned* __restrict__ base,
               const unsigned* __restrict__ cursor,  // post-bin = end of used
               float* __restrict__ I, int n_nodes) {
    __shared__ int accR[PBE_BSIZE];
    __shared__ int accI[PBE_BSIZE];
    for (int j = threadIdx.x; j < PBE_BSIZE; j += 512) { accR[j] = 0; accI[j] = 0; }
    __syncthreads();
    const int b = blockIdx.x;
    const unsigned lo = base[b], hi = cursor[b];
    for (unsigned t = lo + threadIdx.x; t < hi; t += 512) {
        ull p = __builtin_nontemporal_load(rec + t);
        H2U um; um.u = (unsigned)p;
        unsigned dl = (unsigned)(p >> 32);
        atomicAdd(&accR[dl], __float2int_rn(__low2float(um.h) * PBE_SCALE_LDS));
        atomicAdd(&accI[dl], __float2int_rn(__high2float(um.h) * PBE_SCALE_LDS));
    }
    __syncthreads();
    const int node0 = b << PBE_BSHIFT;
    for (int j = threadIdx.x; j < PBE_BSIZE; j += 512) {
        int n = node0 + j;
        if (n < n_nodes) {
            I[2 * n + 0] = accR[j] * PBE_INV_SCALE_LDS;
            I[2 * n + 1] = accI[j] * PBE_INV_SCALE_LDS;
        }
    }
}

// ---------------- fallback: per-edge packed 64-bit atomic --------------------
__device__ __forceinline__ void pbe_edge_one(float2 gb, int s, int d,
                                             const float2* __restrict__ V,
                                             ull* __restrict__ Iq) {
    float2 v = V[s];
    float mr = gb.x * v.x - gb.y * v.y;
    float mi = gb.x * v.y + gb.y * v.x;
    int qr = __float2int_rn(mr * PBE_SCALE64);
    int qi = __float2int_rn(mi * PBE_SCALE64);
    ull pack = ((ull)(unsigned)qr << 32) + (ull)(long long)qi;
    atomicAdd(&Iq[d], pack);
}

__global__ void __launch_bounds__(PBE_NT)
pbe_edge_scatter(const float2* __restrict__ edge_attr,
                 const int* __restrict__ src,
                 const int* __restrict__ dst,
                 const float2* __restrict__ V,
                 ull* __restrict__ Iq,
                 int e_total) {
    int i = blockIdx.x * blockDim.x + threadIdx.x;
    const int stride = gridDim.x * blockDim.x;
    for (; i + 3 * stride < e_total; i += 4 * stride) {
        int ia = i, ib = i + stride, ic = i + 2 * stride, id = i + 3 * stride;
        float2 ga = ld_nt_f2(edge_attr + ia);
        float2 gb = ld_nt_f2(edge_attr + ib);
        float2 gc = ld_nt_f2(edge_attr + ic);
        float2 gd = ld_nt_f2(edge_attr + id);
        int sa = ld_nt_i(src + ia), sb = ld_nt_i(src + ib);
        int sc = ld_nt_i(src + ic), sd = ld_nt_i(src + id);
        int da = ld_nt_i(dst + ia), db = ld_nt_i(dst + ib);
        int dc = ld_nt_i(dst + ic), dd = ld_nt_i(dst + id);
        pbe_edge_one(ga, sa, da, V, Iq);
        pbe_edge_one(gb, sb, db, V, Iq);
        pbe_edge_one(gc, sc, dc, V, Iq);
        pbe_edge_one(gd, sd, dd, V, Iq);
    }
    for (; i < e_total; i += stride) {
        float2 g = ld_nt_f2(edge_attr + i);
        pbe_edge_one(g, ld_nt_i(src + i), ld_nt_i(dst + i), V, Iq);
    }
}

__global__ void pbe_unpack_iq(ull* __restrict__ Iq, float* __restrict__ I, int n) {
    int i = blockIdx.x * blockDim.x + threadIdx.x;
    int stride = gridDim.x * blockDim.x;
    for (; i < n; i += stride) {
        long long q = (long long)Iq[i];
        int lo = (int)(unsigned)(q & 0xFFFFFFFFll);
        int hi = (int)((q - (long long)lo) >> 32);
        I[2 * i + 0] = hi * PBE_INV_SCALE64;
        I[2 * i + 1] = lo * PBE_INV_SCALE64;
    }
}

// ---------------- residual + reduction ---------------------------------------
__global__ void pbe_reduce(const float* __restrict__ V,
                           const float* __restrict__ S,
                           const float* __restrict__ I,
                           float* __restrict__ sums, int n) {
    float a0 = 0.f, a1 = 0.f, a2 = 0.f;
    int i = blockIdx.x * blockDim.x + threadIdx.x;
    int stride = gridDim.x * blockDim.x;
    for (; i < n; i += stride) {
        float2 v  = reinterpret_cast<const float2*>(V)[i];
        float2 sb = reinterpret_cast<const float2*>(S)[i];
        float2 cc = reinterpret_cast<const float2*>(I)[i];
        float rr = sb.x - (v.x * cc.x + v.y * cc.y);
        float ri = sb.y - (v.y * cc.x - v.x * cc.y);
        a0 += sqrtf(rr * rr + ri * ri);
        a1 += fabsf(rr);
        a2 += fabsf(ri);
    }
    #pragma unroll
    for (int off = 32; off > 0; off >>= 1) {
        a0 += __shfl_down(a0, off);
        a1 += __shfl_down(a1, off);
        a2 += __shfl_down(a2, off);
    }
    __shared__ float sm[3][PBE_NT / 64];
    int wid  = threadIdx.x >> 6;
    int lane = threadIdx.x & 63;
    if (lane == 0) { sm[0][wid] = a0; sm[1][wid] = a1; sm[2][wid] = a2; }
    __syncthreads();
    if (threadIdx.x == 0) {
        float t0 = 0.f, t1 = 0.f, t2 = 0.f;
        #pragma unroll
        for (int w = 0; w < PBE_NT / 64; ++w) {
            t0 += sm[0][w]; t1 += sm[1][w]; t2 += sm[2][w];
        }
        atomicAdd(&sums[0], t0);
        atomicAdd(&sums[1], t1);
        atomicAdd(&sums[2], t2);
    }
}

__global__ void pbe_finalize(const float* __restrict__ sums,
                             float* __restrict__ out, float inv_n) {
    int t = threadIdx.x;
    if (t < 3) out[t] = sums[t] * inv_n;
}

static inline size_t align256(size_t x) { return (x + 255) & ~(size_t)255; }

extern "C" void kernel_launch(void* const* d_in, const int* in_sizes, int n_in,
                              void* d_out, int out_size, void* d_ws, size_t ws_size,
                              hipStream_t stream) {
    const float* pred      = (const float*)d_in[0];
    const float* target    = (const float*)d_in[1];
    const float* edge_attr = (const float*)d_in[2];
    const int*   edge_idx  = (const int*)d_in[3]; // [2, E] int32
    const int*   mask      = (const int*)d_in[4]; // bool -> int32

    const int n_nodes = in_sizes[0] / 6;
    const int n_edges = in_sizes[2] / 2;
    const int* src = edge_idx;
    const int* dst = edge_idx + n_edges;

    const int NBa     = (n_nodes + PBE_BSIZE - 1) / PBE_BSIZE;  // active buckets
    const int n_tiles = (n_edges + PBE_TILE - 1) / PBE_TILE;

    char* w = (char*)d_ws;
    size_t oV    = 0;
    size_t oS    = align256(oV + (size_t)2 * n_nodes * 4);
    size_t oI    = align256(oS + (size_t)2 * n_nodes * 4);
    size_t oVh   = align256(oI + (size_t)2 * n_nodes * 4);
    size_t oRec  = align256(oVh + (size_t)n_nodes * 4);
    size_t oHist = align256(oRec + (size_t)n_edges * 8);   // exact capacity
    size_t oBase = align256(oHist + PBE_NB * 4);
    size_t oCur  = align256(oBase + PBE_NB * 4);
    size_t oSums = align256(oCur + PBE_NB * 4);
    size_t need  = oSums + 3 * 4;

    float*    V      = (float*)(w + oV);
    float*    S      = (float*)(w + oS);
    float*    I      = (float*)(w + oI);
    unsigned* Vh     = (unsigned*)(w + oVh);
    ull*      rec    = (ull*)(w + oRec);
    unsigned* hist_g = (unsigned*)(w + oHist);
    unsigned* base   = (unsigned*)(w + oBase);
    unsigned* cursor = (unsigned*)(w + oCur);
    float*    sums   = (float*)(w + oSums);

    const bool fast = (ws_size >= need) && (NBa <= PBE_NB);

    const int T = PBE_NT;
    int grid_nodes = (n_nodes + T - 1) / T;
    if (grid_nodes > 4096) grid_nodes = 4096;

    if (fast) {
        hipMemsetAsync(hist_g, 0, PBE_NB * sizeof(unsigned), stream);
        hipMemsetAsync(sums, 0, 3 * sizeof(float), stream);

        pbe_node_prep<<<grid_nodes, T, 0, stream>>>(pred, target, mask, V, S, Vh, n_nodes);
        pbe_hist<<<1024, T, 0, stream>>>(dst, hist_g, n_edges);
        pbe_prefix<<<1, PBE_NB, 0, stream>>>(hist_g, base, cursor);
        pbe_bin<<<n_tiles, PBE_NTB, 0, stream>>>((const float2*)edge_attr, src, dst,
                                                 Vh, rec, cursor, n_edges);
        pbe_bucket_acc<<<NBa, 512, 0, stream>>>(rec, base, cursor, I, n_nodes);
        pbe_reduce<<<grid_nodes, T, 0, stream>>>(V, S, I, sums, n_nodes);
        pbe_finalize<<<1, 64, 0, stream>>>(sums, (float*)d_out, 1.0f / (float)n_nodes);
    } else {
        ull* Iq = (ull*)(w + oI);
        float* sums_fb = (float*)(w + oVh);
        hipMemsetAsync(Iq, 0, (size_t)n_nodes * 8, stream);
        hipMemsetAsync(sums_fb, 0, 3 * sizeof(float), stream);
        int grid_edges = (n_edges + T - 1) / T;
        if (grid_edges > 8192) grid_edges = 8192;
        pbe_node_prep<<<grid_nodes, T, 0, stream>>>(pred, target, mask, V, S,
                                                    (unsigned*)nullptr, n_nodes);
        pbe_edge_scatter<<<grid_edges, T, 0, stream>>>(
            (const float2*)edge_attr, src, dst, (const float2*)V, Iq, n_edges);
        pbe_unpack_iq<<<grid_nodes, T, 0, stream>>>(Iq, (float*)(w + oI), n_nodes);
        pbe_reduce<<<grid_nodes, T, 0, stream>>>(V, S, (float*)(w + oI), sums_fb, n_nodes);
        pbe_finalize<<<1, 64, 0, stream>>>(sums_fb, (float*)d_out, 1.0f / (float)n_nodes);
    }
}

// Round 7
// 678.722 us; speedup vs baseline: 2.9261x; 1.2269x over previous
//
#include <hip/hip_runtime.h>
#include <hip/hip_fp16.h>
#include <math.h>

// PBELoss: power-flow residual loss.
// residual_i = Sbus_i - V_i * conj( sum_{e: dst(e)=i} Y_e * V_{src(e)} )
// out = [ mean|res|, mean|Re res|, mean|Im res| ]
//
// Fast path: dst-binned aggregation. Bin pass stages each 4096-edge tile's
// records in LDS sorted by bucket (bucket id packed in record bits 44..52),
// then copies out wave-coalesced with NT stores. Per-bucket accumulate is
// exact int32 fixed-point in LDS (deterministic) fused with the residual
// reduction (no I buffer round-trip).
// Fallback (small ws): per-edge packed 64-bit fixed-point atomicAdd.

#define PBE_NT     256
#define PBE_NB     512          // buckets
#define PBE_BSHIFT 12           // 4096 nodes/bucket
#define PBE_BSIZE  4096
#define PBE_TILE   4096
#define PBE_NTB    512          // threads in bin kernel
#define PBE_EPT    (PBE_TILE / PBE_NTB)   // 8

#define PBE_SCALE64       2097152.0f      // 2^21 (fallback)
#define PBE_INV_SCALE64   (1.0f / 2097152.0f)
#define PBE_SCALE_LDS     524288.0f       // 2^19 (bucket accumulate)
#define PBE_INV_SCALE_LDS (1.0f / 524288.0f)

typedef unsigned long long ull;
typedef int iv4 __attribute__((ext_vector_type(4)));
union H2U { __half2 h; unsigned u; };

__device__ __forceinline__ float2 ld_nt_f2(const float2* p) {
    double d = __builtin_nontemporal_load(reinterpret_cast<const double*>(p));
    union { double d; float2 f; } u; u.d = d;
    return u.f;
}
__device__ __forceinline__ int ld_nt_i(const int* p) {
    return __builtin_nontemporal_load(p);
}
__device__ __forceinline__ int2 ld_nt_i2(const int* p) {
    long long v = __builtin_nontemporal_load(reinterpret_cast<const long long*>(p));
    int2 r; r.x = (int)(unsigned)(v & 0xFFFFFFFFll); r.y = (int)(v >> 32);
    return r;
}
__device__ __forceinline__ iv4 ld_nt_iv4(const int* p) {
    return __builtin_nontemporal_load(reinterpret_cast<const iv4*>(p));
}

// ---------------- node prep (vectorized) -------------------------------------
__global__ void pbe_node_prep(const float* __restrict__ pred,
                              const float* __restrict__ target,
                              const int* __restrict__ mask,
                              float* __restrict__ V,
                              float* __restrict__ S,
                              unsigned* __restrict__ Vh,   // may be null
                              int n) {
    int i = blockIdx.x * blockDim.x + threadIdx.x;
    int stride = gridDim.x * blockDim.x;
    for (; i < n; i += stride) {
        int b = 6 * i;
        float2 p0 = ld_nt_f2((const float2*)(pred + b));
        float2 p1 = ld_nt_f2((const float2*)(pred + b + 2));
        float2 p2 = ld_nt_f2((const float2*)(pred + b + 4));
        float2 t0 = ld_nt_f2((const float2*)(target + b));
        float2 t1 = ld_nt_f2((const float2*)(target + b + 2));
        float2 t2 = ld_nt_f2((const float2*)(target + b + 4));
        int2 m0 = ld_nt_i2(mask + b);
        int2 m1 = ld_nt_i2(mask + b + 2);
        int2 m2 = ld_nt_i2(mask + b + 4);
        float pd = m0.x ? p0.x : t0.x;
        float qd = m0.y ? p0.y : t0.y;
        float pg = m1.x ? p1.x : t1.x;
        float qg = m1.y ? p1.y : t1.y;
        float vm = m2.x ? p2.x : t2.x;
        float va = m2.y ? p2.y : t2.y;
        float sn, cs;
        sincosf(va, &sn, &cs);
        float vr = vm * cs, vi = vm * sn;
        V[2 * i + 0] = vr;
        V[2 * i + 1] = vi;
        S[2 * i + 0] = pg - pd;
        S[2 * i + 1] = qg - qd;
        if (Vh) { H2U u; u.h = __floats2half2_rn(vr, vi); Vh[i] = u.u; }
    }
}

// ---------------- pass A: global bucket histogram ----------------------------
__global__ void pbe_hist(const int* __restrict__ dst,
                         unsigned* __restrict__ hist_g, int e_total) {
    __shared__ unsigned h[PBE_NB];
    for (int b = threadIdx.x; b < PBE_NB; b += blockDim.x) h[b] = 0;
    __syncthreads();
    int n4 = e_total >> 2;
    int i = blockIdx.x * blockDim.x + threadIdx.x;
    int stride = gridDim.x * blockDim.x;
    for (; i < n4; i += stride) {
        iv4 v = ld_nt_iv4(dst + 4 * i);
        atomicAdd(&h[((unsigned)v[0]) >> PBE_BSHIFT], 1u);
        atomicAdd(&h[((unsigned)v[1]) >> PBE_BSHIFT], 1u);
        atomicAdd(&h[((unsigned)v[2]) >> PBE_BSHIFT], 1u);
        atomicAdd(&h[((unsigned)v[3]) >> PBE_BSHIFT], 1u);
    }
    if (blockIdx.x == 0) {
        for (int t = (n4 << 2) + threadIdx.x; t < e_total; t += blockDim.x)
            atomicAdd(&h[((unsigned)dst[t]) >> PBE_BSHIFT], 1u);
    }
    __syncthreads();
    for (int b = threadIdx.x; b < PBE_NB; b += blockDim.x)
        if (h[b]) atomicAdd(&hist_g[b], h[b]);
}

// ---------------- pass B: exclusive prefix -> base, cursor -------------------
__global__ void pbe_prefix(const unsigned* __restrict__ hist_g,
                           unsigned* __restrict__ base,
                           unsigned* __restrict__ cursor) {
    __shared__ unsigned tmp[PBE_NB];
    int t = threadIdx.x;
    unsigned mine = hist_g[t];
    tmp[t] = mine;
    __syncthreads();
    for (int o = 1; o < PBE_NB; o <<= 1) {
        unsigned u = (t >= o) ? tmp[t - o] : 0u;
        __syncthreads();
        tmp[t] += u;
        __syncthreads();
    }
    unsigned excl = tmp[t] - mine;
    base[t] = excl;
    cursor[t] = excl;
}

// ---------------- pass C: bin via LDS staging + coalesced copy-out -----------
__global__ void __launch_bounds__(PBE_NTB)
pbe_bin(const float2* __restrict__ Y,
        const int* __restrict__ src,
        const int* __restrict__ dst,
        const unsigned* __restrict__ Vh,
        ull* __restrict__ rec,
        unsigned* __restrict__ cursor,
        int e_total) {
    __shared__ unsigned hist[PBE_NB];
    __shared__ unsigned lbase[PBE_NB];    // per-tile exclusive prefix (LDS pos)
    __shared__ unsigned delta[PBE_NB];    // global_off - lbase
    __shared__ unsigned lcur[PBE_NB];
    __shared__ unsigned wsum[8];
    __shared__ ull recs[PBE_TILE];        // 32 KB staged records (bkt in bits 44+)

    const int tile0 = blockIdx.x * PBE_TILE;
    const int tid = threadIdx.x;
    hist[tid] = 0; lcur[tid] = 0;         // PBE_NTB == PBE_NB == 512
    __syncthreads();

    // phase 1: dst loads + tile histogram
    int d[PBE_EPT];
    #pragma unroll
    for (int k = 0; k < PBE_EPT; ++k) {
        int i = tile0 + k * PBE_NTB + tid;
        d[k] = (i < e_total) ? ld_nt_i(dst + i) : -1;
    }
    #pragma unroll
    for (int k = 0; k < PBE_EPT; ++k)
        if (d[k] >= 0) atomicAdd(&hist[((unsigned)d[k]) >> PBE_BSHIFT], 1u);
    __syncthreads();

    // phase 2: shfl wave-scan + cross-wave scan + exact global reservation
    {
        unsigned mine = hist[tid];
        unsigned v = mine;
        #pragma unroll
        for (int o = 1; o < 64; o <<= 1) {
            unsigned u = __shfl_up(v, o);
            if ((tid & 63) >= o) v += u;
        }
        if ((tid & 63) == 63) wsum[tid >> 6] = v;
        __syncthreads();
        if (tid == 0) {
            unsigned acc = 0;
            #pragma unroll
            for (int wv = 0; wv < 8; ++wv) {
                unsigned t = wsum[wv]; wsum[wv] = acc; acc += t;
            }
        }
        __syncthreads();
        unsigned incl = v + wsum[tid >> 6];
        unsigned excl = incl - mine;
        lbase[tid] = excl;
        unsigned g = mine ? atomicAdd(&cursor[tid], mine) : 0u;
        delta[tid] = g - excl;            // unsigned wrap is fine
    }
    __syncthreads();

    // phase 3: batched gathers -> scatter records into LDS by bucket rank
    #pragma unroll
    for (int h = 0; h < PBE_EPT / 8; ++h) {
        int s8[8]; unsigned uv[8]; float2 y8[8];
        #pragma unroll
        for (int j = 0; j < 8; ++j) {
            int k = h * 8 + j;
            int i = tile0 + k * PBE_NTB + tid;
            s8[j] = (d[k] >= 0) ? ld_nt_i(src + i) : 0;
        }
        #pragma unroll
        for (int j = 0; j < 8; ++j) uv[j] = Vh[s8[j]];   // random 4B gathers
        #pragma unroll
        for (int j = 0; j < 8; ++j) {
            int k = h * 8 + j;
            int i = tile0 + k * PBE_NTB + tid;
            y8[j] = (d[k] >= 0) ? ld_nt_f2(Y + i) : make_float2(0.f, 0.f);
        }
        #pragma unroll
        for (int j = 0; j < 8; ++j) {
            int k = h * 8 + j;
            if (d[k] < 0) continue;
            unsigned b = ((unsigned)d[k]) >> PBE_BSHIFT;
            unsigned pos = lbase[b] + atomicAdd(&lcur[b], 1u);
            H2U uvh; uvh.u = uv[j];
            float vr = __low2float(uvh.h), vi = __high2float(uvh.h);
            float mr = y8[j].x * vr - y8[j].y * vi;
            float mi = y8[j].x * vi + y8[j].y * vr;
            H2U um; um.h = __floats2half2_rn(mr, mi);
            recs[pos] = ((ull)b << 44)
                      | ((ull)(unsigned)(d[k] & (PBE_BSIZE - 1)) << 32)
                      | um.u;
        }
    }
    __syncthreads();

    // phase 4: coalesced copy-out; strip bucket bits. NT store keeps rec
    // lines out of L2 (preserves Vh residency).
    unsigned staged = lbase[PBE_NB - 1] + hist[PBE_NB - 1];
    for (unsigned j = tid; j < staged; j += PBE_NTB) {
        ull r = recs[j];
        unsigned b = (unsigned)(r >> 44);
        __builtin_nontemporal_store(r & 0xFFFFFFFFFFFull, &rec[j + delta[b]]);
    }
}

// ---------------- pass D: per-bucket accumulate + fused residual reduce ------
__global__ void __launch_bounds__(512)
pbe_bucket_acc_red(const ull* __restrict__ rec,
                   const unsigned* __restrict__ base,
                   const unsigned* __restrict__ cursor, // post-bin end
                   const float* __restrict__ V,
                   const float* __restrict__ S,
                   float* __restrict__ sums, int n_nodes) {
    __shared__ int accR[PBE_BSIZE];
    __shared__ int accI[PBE_BSIZE];
    for (int j = threadIdx.x; j < PBE_BSIZE; j += 512) { accR[j] = 0; accI[j] = 0; }
    __syncthreads();
    const int b = blockIdx.x;
    const unsigned lo = base[b], hi = cursor[b];
    for (unsigned t = lo + threadIdx.x; t < hi; t += 512) {
        ull p = __builtin_nontemporal_load(rec + t);
        H2U um; um.u = (unsigned)p;
        unsigned dl = (unsigned)(p >> 32) & (PBE_BSIZE - 1);
        atomicAdd(&accR[dl], __float2int_rn(__low2float(um.h) * PBE_SCALE_LDS));
        atomicAdd(&accI[dl], __float2int_rn(__high2float(um.h) * PBE_SCALE_LDS));
    }
    __syncthreads();
    // fused residual + reduction over this bucket's node range
    const int node0 = b << PBE_BSHIFT;
    float a0 = 0.f, a1 = 0.f, a2 = 0.f;
    for (int j = threadIdx.x; j < PBE_BSIZE; j += 512) {
        int n = node0 + j;
        if (n < n_nodes) {
            float2 v  = reinterpret_cast<const float2*>(V)[n];
            float2 sb = reinterpret_cast<const float2*>(S)[n];
            float cr = accR[j] * PBE_INV_SCALE_LDS;
            float ci = accI[j] * PBE_INV_SCALE_LDS;
            float rr = sb.x - (v.x * cr + v.y * ci);
            float ri = sb.y - (v.y * cr - v.x * ci);
            a0 += sqrtf(rr * rr + ri * ri);
            a1 += fabsf(rr);
            a2 += fabsf(ri);
        }
    }
    #pragma unroll
    for (int off = 32; off > 0; off >>= 1) {
        a0 += __shfl_down(a0, off);
        a1 += __shfl_down(a1, off);
        a2 += __shfl_down(a2, off);
    }
    __shared__ float sm[3][8];
    int wid  = threadIdx.x >> 6;
    int lane = threadIdx.x & 63;
    if (lane == 0) { sm[0][wid] = a0; sm[1][wid] = a1; sm[2][wid] = a2; }
    __syncthreads();
    if (threadIdx.x == 0) {
        float t0 = 0.f, t1 = 0.f, t2 = 0.f;
        #pragma unroll
        for (int wv = 0; wv < 8; ++wv) {
            t0 += sm[0][wv]; t1 += sm[1][wv]; t2 += sm[2][wv];
        }
        atomicAdd(&sums[0], t0);
        atomicAdd(&sums[1], t1);
        atomicAdd(&sums[2], t2);
    }
}

// ---------------- fallback: per-edge packed 64-bit atomic --------------------
__device__ __forceinline__ void pbe_edge_one(float2 gb, int s, int d,
                                             const float2* __restrict__ V,
                                             ull* __restrict__ Iq) {
    float2 v = V[s];
    float mr = gb.x * v.x - gb.y * v.y;
    float mi = gb.x * v.y + gb.y * v.x;
    int qr = __float2int_rn(mr * PBE_SCALE64);
    int qi = __float2int_rn(mi * PBE_SCALE64);
    ull pack = ((ull)(unsigned)qr << 32) + (ull)(long long)qi;
    atomicAdd(&Iq[d], pack);
}

__global__ void __launch_bounds__(PBE_NT)
pbe_edge_scatter(const float2* __restrict__ edge_attr,
                 const int* __restrict__ src,
                 const int* __restrict__ dst,
                 const float2* __restrict__ V,
                 ull* __restrict__ Iq,
                 int e_total) {
    int i = blockIdx.x * blockDim.x + threadIdx.x;
    const int stride = gridDim.x * blockDim.x;
    for (; i + 3 * stride < e_total; i += 4 * stride) {
        int ia = i, ib = i + stride, ic = i + 2 * stride, id = i + 3 * stride;
        float2 ga = ld_nt_f2(edge_attr + ia);
        float2 gb = ld_nt_f2(edge_attr + ib);
        float2 gc = ld_nt_f2(edge_attr + ic);
        float2 gd = ld_nt_f2(edge_attr + id);
        int sa = ld_nt_i(src + ia), sb = ld_nt_i(src + ib);
        int sc = ld_nt_i(src + ic), sd = ld_nt_i(src + id);
        int da = ld_nt_i(dst + ia), db = ld_nt_i(dst + ib);
        int dc = ld_nt_i(dst + ic), dd = ld_nt_i(dst + id);
        pbe_edge_one(ga, sa, da, V, Iq);
        pbe_edge_one(gb, sb, db, V, Iq);
        pbe_edge_one(gc, sc, dc, V, Iq);
        pbe_edge_one(gd, sd, dd, V, Iq);
    }
    for (; i < e_total; i += stride) {
        float2 g = ld_nt_f2(edge_attr + i);
        pbe_edge_one(g, ld_nt_i(src + i), ld_nt_i(dst + i), V, Iq);
    }
}

__global__ void pbe_unpack_iq(ull* __restrict__ Iq, float* __restrict__ I, int n) {
    int i = blockIdx.x * blockDim.x + threadIdx.x;
    int stride = gridDim.x * blockDim.x;
    for (; i < n; i += stride) {
        long long q = (long long)Iq[i];
        int lo = (int)(unsigned)(q & 0xFFFFFFFFll);
        int hi = (int)((q - (long long)lo) >> 32);
        I[2 * i + 0] = hi * PBE_INV_SCALE64;
        I[2 * i + 1] = lo * PBE_INV_SCALE64;
    }
}

__global__ void pbe_reduce(const float* __restrict__ V,
                           const float* __restrict__ S,
                           const float* __restrict__ I,
                           float* __restrict__ sums, int n) {
    float a0 = 0.f, a1 = 0.f, a2 = 0.f;
    int i = blockIdx.x * blockDim.x + threadIdx.x;
    int stride = gridDim.x * blockDim.x;
    for (; i < n; i += stride) {
        float2 v  = reinterpret_cast<const float2*>(V)[i];
        float2 sb = reinterpret_cast<const float2*>(S)[i];
        float2 cc = reinterpret_cast<const float2*>(I)[i];
        float rr = sb.x - (v.x * cc.x + v.y * cc.y);
        float ri = sb.y - (v.y * cc.x - v.x * cc.y);
        a0 += sqrtf(rr * rr + ri * ri);
        a1 += fabsf(rr);
        a2 += fabsf(ri);
    }
    #pragma unroll
    for (int off = 32; off > 0; off >>= 1) {
        a0 += __shfl_down(a0, off);
        a1 += __shfl_down(a1, off);
        a2 += __shfl_down(a2, off);
    }
    __shared__ float sm[3][PBE_NT / 64];
    int wid  = threadIdx.x >> 6;
    int lane = threadIdx.x & 63;
    if (lane == 0) { sm[0][wid] = a0; sm[1][wid] = a1; sm[2][wid] = a2; }
    __syncthreads();
    if (threadIdx.x == 0) {
        float t0 = 0.f, t1 = 0.f, t2 = 0.f;
        #pragma unroll
        for (int w = 0; w < PBE_NT / 64; ++w) {
            t0 += sm[0][w]; t1 += sm[1][w]; t2 += sm[2][w];
        }
        atomicAdd(&sums[0], t0);
        atomicAdd(&sums[1], t1);
        atomicAdd(&sums[2], t2);
    }
}

__global__ void pbe_finalize(const float* __restrict__ sums,
                             float* __restrict__ out, float inv_n) {
    int t = threadIdx.x;
    if (t < 3) out[t] = sums[t] * inv_n;
}

static inline size_t align256(size_t x) { return (x + 255) & ~(size_t)255; }

extern "C" void kernel_launch(void* const* d_in, const int* in_sizes, int n_in,
                              void* d_out, int out_size, void* d_ws, size_t ws_size,
                              hipStream_t stream) {
    const float* pred      = (const float*)d_in[0];
    const float* target    = (const float*)d_in[1];
    const float* edge_attr = (const float*)d_in[2];
    const int*   edge_idx  = (const int*)d_in[3]; // [2, E] int32
    const int*   mask      = (const int*)d_in[4]; // bool -> int32

    const int n_nodes = in_sizes[0] / 6;
    const int n_edges = in_sizes[2] / 2;
    const int* src = edge_idx;
    const int* dst = edge_idx + n_edges;

    const int NBa     = (n_nodes + PBE_BSIZE - 1) / PBE_BSIZE;  // active buckets
    const int n_tiles = (n_edges + PBE_TILE - 1) / PBE_TILE;

    char* w = (char*)d_ws;
    size_t oV    = 0;
    size_t oS    = align256(oV + (size_t)2 * n_nodes * 4);
    size_t oVh   = align256(oS + (size_t)2 * n_nodes * 4);
    size_t oRec  = align256(oVh + (size_t)n_nodes * 4);
    size_t oHist = align256(oRec + (size_t)n_edges * 8);   // exact capacity
    size_t oBase = align256(oHist + PBE_NB * 4);
    size_t oCur  = align256(oBase + PBE_NB * 4);
    size_t oSums = align256(oCur + PBE_NB * 4);
    size_t need  = oSums + 3 * 4;

    float*    V      = (float*)(w + oV);
    float*    S      = (float*)(w + oS);
    unsigned* Vh     = (unsigned*)(w + oVh);
    ull*      rec    = (ull*)(w + oRec);
    unsigned* hist_g = (unsigned*)(w + oHist);
    unsigned* base   = (unsigned*)(w + oBase);
    unsigned* cursor = (unsigned*)(w + oCur);
    float*    sums   = (float*)(w + oSums);

    const bool fast = (ws_size >= need) && (NBa <= PBE_NB);

    const int T = PBE_NT;
    int grid_nodes = (n_nodes + T - 1) / T;
    if (grid_nodes > 4096) grid_nodes = 4096;

    if (fast) {
        hipMemsetAsync(hist_g, 0, PBE_NB * sizeof(unsigned), stream);
        hipMemsetAsync(sums, 0, 3 * sizeof(float), stream);

        pbe_node_prep<<<grid_nodes, T, 0, stream>>>(pred, target, mask, V, S, Vh, n_nodes);
        pbe_hist<<<1024, T, 0, stream>>>(dst, hist_g, n_edges);
        pbe_prefix<<<1, PBE_NB, 0, stream>>>(hist_g, base, cursor);
        pbe_bin<<<n_tiles, PBE_NTB, 0, stream>>>((const float2*)edge_attr, src, dst,
                                                 Vh, rec, cursor, n_edges);
        pbe_bucket_acc_red<<<NBa, 512, 0, stream>>>(rec, base, cursor, V, S,
                                                    sums, n_nodes);
        pbe_finalize<<<1, 64, 0, stream>>>(sums, (float*)d_out, 1.0f / (float)n_nodes);
    } else {
        // fallback: packed 64-bit fixed-point atomics (round-3 scheme)
        ull* Iq = (ull*)(w + oRec);             // plenty of room
        float* I_fb = (float*)(w + oVh);        // unused Vh region? too small;
        I_fb = (float*)(w + oRec) + 2 * (size_t)n_nodes;  // after Iq? overlap!
        // place I after Iq region explicitly:
        I_fb = (float*)((char*)(w + oRec) + align256((size_t)n_nodes * 8));
        float* sums_fb = (float*)(w + oVh);
        hipMemsetAsync(Iq, 0, (size_t)n_nodes * 8, stream);
        hipMemsetAsync(sums_fb, 0, 3 * sizeof(float), stream);
        int grid_edges = (n_edges + T - 1) / T;
        if (grid_edges > 8192) grid_edges = 8192;
        pbe_node_prep<<<grid_nodes, T, 0, stream>>>(pred, target, mask, V, S,
                                                    (unsigned*)nullptr, n_nodes);
        pbe_edge_scatter<<<grid_edges, T, 0, stream>>>(
            (const float2*)edge_attr, src, dst, (const float2*)V, Iq, n_edges);
        pbe_unpack_iq<<<grid_nodes, T, 0, stream>>>(Iq, (float*)Iq, n_nodes);
        pbe_reduce<<<grid_nodes, T, 0, stream>>>(V, S, (float*)Iq, sums_fb, n_nodes);
        pbe_finalize<<<1, 64, 0, stream>>>(sums_fb, (float*)d_out, 1.0f / (float)n_nodes);
    }
}

// Round 8
// 672.273 us; speedup vs baseline: 2.9542x; 1.0096x over previous
//
#include <hip/hip_runtime.h>
#include <hip/hip_fp16.h>
#include <math.h>

// PBELoss: power-flow residual loss.
// residual_i = Sbus_i - V_i * conj( sum_{e: dst(e)=i} Y_e * V_{src(e)} )
// out = [ mean|res|, mean|Re res|, mean|Im res| ]
//
// Fast path: dst-binned aggregation. Bin pass stages each 4096-edge tile's
// records in LDS sorted by bucket (bucket id packed in record bits 44..52),
// then copies out wave-coalesced with NT stores. LDS footprint kept < 40 KB
// so 4 blocks/CU co-reside (gather-latency hiding). Per-bucket accumulate is
// exact int32 fixed-point in LDS (deterministic) fused with the residual
// reduction.
// Fallback (small ws): per-edge packed 64-bit fixed-point atomicAdd.

#define PBE_NT     256
#define PBE_NB     512          // buckets
#define PBE_BSHIFT 12           // 4096 nodes/bucket
#define PBE_BSIZE  4096
#define PBE_TILE   4096
#define PBE_NTB    512          // threads in bin kernel
#define PBE_EPT    (PBE_TILE / PBE_NTB)   // 8

#define PBE_SCALE64       2097152.0f      // 2^21 (fallback)
#define PBE_INV_SCALE64   (1.0f / 2097152.0f)
#define PBE_SCALE_LDS     524288.0f       // 2^19 (bucket accumulate)
#define PBE_INV_SCALE_LDS (1.0f / 524288.0f)

typedef unsigned long long ull;
typedef int iv4 __attribute__((ext_vector_type(4)));
union H2U { __half2 h; unsigned u; };

__device__ __forceinline__ float2 ld_nt_f2(const float2* p) {
    double d = __builtin_nontemporal_load(reinterpret_cast<const double*>(p));
    union { double d; float2 f; } u; u.d = d;
    return u.f;
}
__device__ __forceinline__ int ld_nt_i(const int* p) {
    return __builtin_nontemporal_load(p);
}
__device__ __forceinline__ int2 ld_nt_i2(const int* p) {
    long long v = __builtin_nontemporal_load(reinterpret_cast<const long long*>(p));
    int2 r; r.x = (int)(unsigned)(v & 0xFFFFFFFFll); r.y = (int)(v >> 32);
    return r;
}
__device__ __forceinline__ iv4 ld_nt_iv4(const int* p) {
    return __builtin_nontemporal_load(reinterpret_cast<const iv4*>(p));
}

// ---------------- node prep (vectorized) -------------------------------------
__global__ void pbe_node_prep(const float* __restrict__ pred,
                              const float* __restrict__ target,
                              const int* __restrict__ mask,
                              float* __restrict__ V,
                              float* __restrict__ S,
                              unsigned* __restrict__ Vh,   // may be null
                              int n) {
    int i = blockIdx.x * blockDim.x + threadIdx.x;
    int stride = gridDim.x * blockDim.x;
    for (; i < n; i += stride) {
        int b = 6 * i;
        float2 p0 = ld_nt_f2((const float2*)(pred + b));
        float2 p1 = ld_nt_f2((const float2*)(pred + b + 2));
        float2 p2 = ld_nt_f2((const float2*)(pred + b + 4));
        float2 t0 = ld_nt_f2((const float2*)(target + b));
        float2 t1 = ld_nt_f2((const float2*)(target + b + 2));
        float2 t2 = ld_nt_f2((const float2*)(target + b + 4));
        int2 m0 = ld_nt_i2(mask + b);
        int2 m1 = ld_nt_i2(mask + b + 2);
        int2 m2 = ld_nt_i2(mask + b + 4);
        float pd = m0.x ? p0.x : t0.x;
        float qd = m0.y ? p0.y : t0.y;
        float pg = m1.x ? p1.x : t1.x;
        float qg = m1.y ? p1.y : t1.y;
        float vm = m2.x ? p2.x : t2.x;
        float va = m2.y ? p2.y : t2.y;
        float sn, cs;
        sincosf(va, &sn, &cs);
        float vr = vm * cs, vi = vm * sn;
        V[2 * i + 0] = vr;
        V[2 * i + 1] = vi;
        S[2 * i + 0] = pg - pd;
        S[2 * i + 1] = qg - qd;
        if (Vh) { H2U u; u.h = __floats2half2_rn(vr, vi); Vh[i] = u.u; }
    }
}

// ---------------- pass A: global bucket histogram ----------------------------
__global__ void pbe_hist(const int* __restrict__ dst,
                         unsigned* __restrict__ hist_g, int e_total) {
    __shared__ unsigned h[PBE_NB];
    for (int b = threadIdx.x; b < PBE_NB; b += blockDim.x) h[b] = 0;
    __syncthreads();
    int n4 = e_total >> 2;
    int i = blockIdx.x * blockDim.x + threadIdx.x;
    int stride = gridDim.x * blockDim.x;
    for (; i < n4; i += stride) {
        iv4 v = ld_nt_iv4(dst + 4 * i);
        atomicAdd(&h[((unsigned)v[0]) >> PBE_BSHIFT], 1u);
        atomicAdd(&h[((unsigned)v[1]) >> PBE_BSHIFT], 1u);
        atomicAdd(&h[((unsigned)v[2]) >> PBE_BSHIFT], 1u);
        atomicAdd(&h[((unsigned)v[3]) >> PBE_BSHIFT], 1u);
    }
    if (blockIdx.x == 0) {
        for (int t = (n4 << 2) + threadIdx.x; t < e_total; t += blockDim.x)
            atomicAdd(&h[((unsigned)dst[t]) >> PBE_BSHIFT], 1u);
    }
    __syncthreads();
    for (int b = threadIdx.x; b < PBE_NB; b += blockDim.x)
        if (h[b]) atomicAdd(&hist_g[b], h[b]);
}

// ---------------- pass B: exclusive prefix -> base, cursor -------------------
__global__ void pbe_prefix(const unsigned* __restrict__ hist_g,
                           unsigned* __restrict__ base,
                           unsigned* __restrict__ cursor) {
    __shared__ unsigned tmp[PBE_NB];
    int t = threadIdx.x;
    unsigned mine = hist_g[t];
    tmp[t] = mine;
    __syncthreads();
    for (int o = 1; o < PBE_NB; o <<= 1) {
        unsigned u = (t >= o) ? tmp[t - o] : 0u;
        __syncthreads();
        tmp[t] += u;
        __syncthreads();
    }
    unsigned excl = tmp[t] - mine;
    base[t] = excl;
    cursor[t] = excl;
}

// ---------------- pass C: bin via LDS staging + coalesced copy-out -----------
// LDS budget: hist 2K + lbase 2K + wsum 32 + staged 4 + recs 32K ~= 36.9 KB
// -> 4 blocks/CU (needs <= 40960 B).
__global__ void __launch_bounds__(PBE_NTB)
pbe_bin(const float2* __restrict__ Y,
        const int* __restrict__ src,
        const int* __restrict__ dst,
        const unsigned* __restrict__ Vh,
        ull* __restrict__ rec,
        unsigned* __restrict__ cursor,
        int e_total) {
    __shared__ unsigned hist[PBE_NB];     // phase1: counts; phase2+: delta
    __shared__ unsigned lbase[PBE_NB];    // phase2: excl prefix; phase3: cursor
    __shared__ unsigned wsum[8];
    __shared__ unsigned staged_sh;
    __shared__ ull recs[PBE_TILE];        // 32 KB staged records (bkt bits 44+)

    const int tile0 = blockIdx.x * PBE_TILE;
    const int tid = threadIdx.x;
    hist[tid] = 0;                        // PBE_NTB == PBE_NB == 512
    __syncthreads();

    // phase 1: dst loads + tile histogram
    int d[PBE_EPT];
    #pragma unroll
    for (int k = 0; k < PBE_EPT; ++k) {
        int i = tile0 + k * PBE_NTB + tid;
        d[k] = (i < e_total) ? ld_nt_i(dst + i) : -1;
    }
    #pragma unroll
    for (int k = 0; k < PBE_EPT; ++k)
        if (d[k] >= 0) atomicAdd(&hist[((unsigned)d[k]) >> PBE_BSHIFT], 1u);
    __syncthreads();

    // phase 2: shfl wave-scan + cross-wave scan + exact global reservation.
    // After this phase: lbase[b] = tile-local exclusive prefix (scatter cursor),
    // hist[b] = delta (global_base - local_base), staged_sh = tile record count.
    {
        unsigned mine = hist[tid];
        unsigned v = mine;
        #pragma unroll
        for (int o = 1; o < 64; o <<= 1) {
            unsigned u = __shfl_up(v, o);
            if ((tid & 63) >= o) v += u;
        }
        if ((tid & 63) == 63) wsum[tid >> 6] = v;
        __syncthreads();
        if (tid == 0) {
            unsigned acc = 0;
            #pragma unroll
            for (int wv = 0; wv < 8; ++wv) {
                unsigned t = wsum[wv]; wsum[wv] = acc; acc += t;
            }
        }
        __syncthreads();
        unsigned incl = v + wsum[tid >> 6];
        unsigned excl = incl - mine;
        lbase[tid] = excl;
        if (tid == PBE_NB - 1) staged_sh = incl;
        unsigned g = mine ? atomicAdd(&cursor[tid], mine) : 0u;
        hist[tid] = g - excl;             // delta; per-thread slot, no hazard
    }
    __syncthreads();

    // phase 3: batched gathers -> scatter records into LDS by bucket rank
    // (lbase[b] is atomically post-incremented as the local cursor).
    #pragma unroll
    for (int h = 0; h < PBE_EPT / 8; ++h) {
        int s8[8]; unsigned uv[8]; float2 y8[8];
        #pragma unroll
        for (int j = 0; j < 8; ++j) {
            int k = h * 8 + j;
            int i = tile0 + k * PBE_NTB + tid;
            s8[j] = (d[k] >= 0) ? ld_nt_i(src + i) : 0;
        }
        #pragma unroll
        for (int j = 0; j < 8; ++j) uv[j] = Vh[s8[j]];   // random 4B gathers
        #pragma unroll
        for (int j = 0; j < 8; ++j) {
            int k = h * 8 + j;
            int i = tile0 + k * PBE_NTB + tid;
            y8[j] = (d[k] >= 0) ? ld_nt_f2(Y + i) : make_float2(0.f, 0.f);
        }
        #pragma unroll
        for (int j = 0; j < 8; ++j) {
            int k = h * 8 + j;
            if (d[k] < 0) continue;
            unsigned b = ((unsigned)d[k]) >> PBE_BSHIFT;
            unsigned pos = atomicAdd(&lbase[b], 1u);
            H2U uvh; uvh.u = uv[j];
            float vr = __low2float(uvh.h), vi = __high2float(uvh.h);
            float mr = y8[j].x * vr - y8[j].y * vi;
            float mi = y8[j].x * vi + y8[j].y * vr;
            H2U um; um.h = __floats2half2_rn(mr, mi);
            recs[pos] = ((ull)b << 44)
                      | ((ull)(unsigned)(d[k] & (PBE_BSIZE - 1)) << 32)
                      | um.u;
        }
    }
    __syncthreads();

    // phase 4: coalesced copy-out; strip bucket bits. NT store keeps rec
    // lines out of L2 (preserves Vh residency).
    unsigned staged = staged_sh;
    for (unsigned j = tid; j < staged; j += PBE_NTB) {
        ull r = recs[j];
        unsigned b = (unsigned)(r >> 44);
        __builtin_nontemporal_store(r & 0xFFFFFFFFFFFull, &rec[j + hist[b]]);
    }
}

// ---------------- pass D: per-bucket accumulate + fused residual reduce ------
__global__ void __launch_bounds__(512)
pbe_bucket_acc_red(const ull* __restrict__ rec,
                   const unsigned* __restrict__ base,
                   const unsigned* __restrict__ cursor, // post-bin end
                   const float* __restrict__ V,
                   const float* __restrict__ S,
                   float* __restrict__ sums, int n_nodes) {
    __shared__ int accR[PBE_BSIZE];
    __shared__ int accI[PBE_BSIZE];
    for (int j = threadIdx.x; j < PBE_BSIZE; j += 512) { accR[j] = 0; accI[j] = 0; }
    __syncthreads();
    const int b = blockIdx.x;
    const unsigned lo = base[b], hi = cursor[b];
    for (unsigned t = lo + threadIdx.x; t < hi; t += 512) {
        ull p = __builtin_nontemporal_load(rec + t);
        H2U um; um.u = (unsigned)p;
        unsigned dl = (unsigned)(p >> 32) & (PBE_BSIZE - 1);
        atomicAdd(&accR[dl], __float2int_rn(__low2float(um.h) * PBE_SCALE_LDS));
        atomicAdd(&accI[dl], __float2int_rn(__high2float(um.h) * PBE_SCALE_LDS));
    }
    __syncthreads();
    // fused residual + reduction over this bucket's node range
    const int node0 = b << PBE_BSHIFT;
    float a0 = 0.f, a1 = 0.f, a2 = 0.f;
    for (int j = threadIdx.x; j < PBE_BSIZE; j += 512) {
        int n = node0 + j;
        if (n < n_nodes) {
            float2 v  = reinterpret_cast<const float2*>(V)[n];
            float2 sb = reinterpret_cast<const float2*>(S)[n];
            float cr = accR[j] * PBE_INV_SCALE_LDS;
            float ci = accI[j] * PBE_INV_SCALE_LDS;
            float rr = sb.x - (v.x * cr + v.y * ci);
            float ri = sb.y - (v.y * cr - v.x * ci);
            a0 += sqrtf(rr * rr + ri * ri);
            a1 += fabsf(rr);
            a2 += fabsf(ri);
        }
    }
    #pragma unroll
    for (int off = 32; off > 0; off >>= 1) {
        a0 += __shfl_down(a0, off);
        a1 += __shfl_down(a1, off);
        a2 += __shfl_down(a2, off);
    }
    __shared__ float sm[3][8];
    int wid  = threadIdx.x >> 6;
    int lane = threadIdx.x & 63;
    if (lane == 0) { sm[0][wid] = a0; sm[1][wid] = a1; sm[2][wid] = a2; }
    __syncthreads();
    if (threadIdx.x == 0) {
        float t0 = 0.f, t1 = 0.f, t2 = 0.f;
        #pragma unroll
        for (int wv = 0; wv < 8; ++wv) {
            t0 += sm[0][wv]; t1 += sm[1][wv]; t2 += sm[2][wv];
        }
        atomicAdd(&sums[0], t0);
        atomicAdd(&sums[1], t1);
        atomicAdd(&sums[2], t2);
    }
}

// ---------------- fallback: per-edge packed 64-bit atomic --------------------
__device__ __forceinline__ void pbe_edge_one(float2 gb, int s, int d,
                                             const float2* __restrict__ V,
                                             ull* __restrict__ Iq) {
    float2 v = V[s];
    float mr = gb.x * v.x - gb.y * v.y;
    float mi = gb.x * v.y + gb.y * v.x;
    int qr = __float2int_rn(mr * PBE_SCALE64);
    int qi = __float2int_rn(mi * PBE_SCALE64);
    ull pack = ((ull)(unsigned)qr << 32) + (ull)(long long)qi;
    atomicAdd(&Iq[d], pack);
}

__global__ void __launch_bounds__(PBE_NT)
pbe_edge_scatter(const float2* __restrict__ edge_attr,
                 const int* __restrict__ src,
                 const int* __restrict__ dst,
                 const float2* __restrict__ V,
                 ull* __restrict__ Iq,
                 int e_total) {
    int i = blockIdx.x * blockDim.x + threadIdx.x;
    const int stride = gridDim.x * blockDim.x;
    for (; i + 3 * stride < e_total; i += 4 * stride) {
        int ia = i, ib = i + stride, ic = i + 2 * stride, id = i + 3 * stride;
        float2 ga = ld_nt_f2(edge_attr + ia);
        float2 gb = ld_nt_f2(edge_attr + ib);
        float2 gc = ld_nt_f2(edge_attr + ic);
        float2 gd = ld_nt_f2(edge_attr + id);
        int sa = ld_nt_i(src + ia), sb = ld_nt_i(src + ib);
        int sc = ld_nt_i(src + ic), sd = ld_nt_i(src + id);
        int da = ld_nt_i(dst + ia), db = ld_nt_i(dst + ib);
        int dc = ld_nt_i(dst + ic), dd = ld_nt_i(dst + id);
        pbe_edge_one(ga, sa, da, V, Iq);
        pbe_edge_one(gb, sb, db, V, Iq);
        pbe_edge_one(gc, sc, dc, V, Iq);
        pbe_edge_one(gd, sd, dd, V, Iq);
    }
    for (; i < e_total; i += stride) {
        float2 g = ld_nt_f2(edge_attr + i);
        pbe_edge_one(g, ld_nt_i(src + i), ld_nt_i(dst + i), V, Iq);
    }
}

__global__ void pbe_unpack_iq(ull* __restrict__ Iq, float* __restrict__ I, int n) {
    int i = blockIdx.x * blockDim.x + threadIdx.x;
    int stride = gridDim.x * blockDim.x;
    for (; i < n; i += stride) {
        long long q = (long long)Iq[i];
        int lo = (int)(unsigned)(q & 0xFFFFFFFFll);
        int hi = (int)((q - (long long)lo) >> 32);
        I[2 * i + 0] = hi * PBE_INV_SCALE64;
        I[2 * i + 1] = lo * PBE_INV_SCALE64;
    }
}

__global__ void pbe_reduce(const float* __restrict__ V,
                           const float* __restrict__ S,
                           const float* __restrict__ I,
                           float* __restrict__ sums, int n) {
    float a0 = 0.f, a1 = 0.f, a2 = 0.f;
    int i = blockIdx.x * blockDim.x + threadIdx.x;
    int stride = gridDim.x * blockDim.x;
    for (; i < n; i += stride) {
        float2 v  = reinterpret_cast<const float2*>(V)[i];
        float2 sb = reinterpret_cast<const float2*>(S)[i];
        float2 cc = reinterpret_cast<const float2*>(I)[i];
        float rr = sb.x - (v.x * cc.x + v.y * cc.y);
        float ri = sb.y - (v.y * cc.x - v.x * cc.y);
        a0 += sqrtf(rr * rr + ri * ri);
        a1 += fabsf(rr);
        a2 += fabsf(ri);
    }
    #pragma unroll
    for (int off = 32; off > 0; off >>= 1) {
        a0 += __shfl_down(a0, off);
        a1 += __shfl_down(a1, off);
        a2 += __shfl_down(a2, off);
    }
    __shared__ float sm[3][PBE_NT / 64];
    int wid  = threadIdx.x >> 6;
    int lane = threadIdx.x & 63;
    if (lane == 0) { sm[0][wid] = a0; sm[1][wid] = a1; sm[2][wid] = a2; }
    __syncthreads();
    if (threadIdx.x == 0) {
        float t0 = 0.f, t1 = 0.f, t2 = 0.f;
        #pragma unroll
        for (int w = 0; w < PBE_NT / 64; ++w) {
            t0 += sm[0][w]; t1 += sm[1][w]; t2 += sm[2][w];
        }
        atomicAdd(&sums[0], t0);
        atomicAdd(&sums[1], t1);
        atomicAdd(&sums[2], t2);
    }
}

__global__ void pbe_finalize(const float* __restrict__ sums,
                             float* __restrict__ out, float inv_n) {
    int t = threadIdx.x;
    if (t < 3) out[t] = sums[t] * inv_n;
}

static inline size_t align256(size_t x) { return (x + 255) & ~(size_t)255; }

extern "C" void kernel_launch(void* const* d_in, const int* in_sizes, int n_in,
                              void* d_out, int out_size, void* d_ws, size_t ws_size,
                              hipStream_t stream) {
    const float* pred      = (const float*)d_in[0];
    const float* target    = (const float*)d_in[1];
    const float* edge_attr = (const float*)d_in[2];
    const int*   edge_idx  = (const int*)d_in[3]; // [2, E] int32
    const int*   mask      = (const int*)d_in[4]; // bool -> int32

    const int n_nodes = in_sizes[0] / 6;
    const int n_edges = in_sizes[2] / 2;
    const int* src = edge_idx;
    const int* dst = edge_idx + n_edges;

    const int NBa     = (n_nodes + PBE_BSIZE - 1) / PBE_BSIZE;  // active buckets
    const int n_tiles = (n_edges + PBE_TILE - 1) / PBE_TILE;

    char* w = (char*)d_ws;
    size_t oV    = 0;
    size_t oS    = align256(oV + (size_t)2 * n_nodes * 4);
    size_t oVh   = align256(oS + (size_t)2 * n_nodes * 4);
    size_t oRec  = align256(oVh + (size_t)n_nodes * 4);
    size_t oHist = align256(oRec + (size_t)n_edges * 8);   // exact capacity
    size_t oBase = align256(oHist + PBE_NB * 4);
    size_t oCur  = align256(oBase + PBE_NB * 4);
    size_t oSums = align256(oCur + PBE_NB * 4);
    size_t need  = oSums + 3 * 4;

    float*    V      = (float*)(w + oV);
    float*    S      = (float*)(w + oS);
    unsigned* Vh     = (unsigned*)(w + oVh);
    ull*      rec    = (ull*)(w + oRec);
    unsigned* hist_g = (unsigned*)(w + oHist);
    unsigned* base   = (unsigned*)(w + oBase);
    unsigned* cursor = (unsigned*)(w + oCur);
    float*    sums   = (float*)(w + oSums);

    const bool fast = (ws_size >= need) && (NBa <= PBE_NB);

    const int T = PBE_NT;
    int grid_nodes = (n_nodes + T - 1) / T;
    if (grid_nodes > 4096) grid_nodes = 4096;

    if (fast) {
        hipMemsetAsync(hist_g, 0, PBE_NB * sizeof(unsigned), stream);
        hipMemsetAsync(sums, 0, 3 * sizeof(float), stream);

        pbe_node_prep<<<grid_nodes, T, 0, stream>>>(pred, target, mask, V, S, Vh, n_nodes);
        pbe_hist<<<1024, T, 0, stream>>>(dst, hist_g, n_edges);
        pbe_prefix<<<1, PBE_NB, 0, stream>>>(hist_g, base, cursor);
        pbe_bin<<<n_tiles, PBE_NTB, 0, stream>>>((const float2*)edge_attr, src, dst,
                                                 Vh, rec, cursor, n_edges);
        pbe_bucket_acc_red<<<NBa, 512, 0, stream>>>(rec, base, cursor, V, S,
                                                    sums, n_nodes);
        pbe_finalize<<<1, 64, 0, stream>>>(sums, (float*)d_out, 1.0f / (float)n_nodes);
    } else {
        // fallback: packed 64-bit fixed-point atomics (round-3 scheme)
        ull* Iq = (ull*)(w + oRec);
        float* sums_fb = (float*)(w + oVh);
        hipMemsetAsync(Iq, 0, (size_t)n_nodes * 8, stream);
        hipMemsetAsync(sums_fb, 0, 3 * sizeof(float), stream);
        int grid_edges = (n_edges + T - 1) / T;
        if (grid_edges > 8192) grid_edges = 8192;
        pbe_node_prep<<<grid_nodes, T, 0, stream>>>(pred, target, mask, V, S,
                                                    (unsigned*)nullptr, n_nodes);
        pbe_edge_scatter<<<grid_edges, T, 0, stream>>>(
            (const float2*)edge_attr, src, dst, (const float2*)V, Iq, n_edges);
        pbe_unpack_iq<<<grid_nodes, T, 0, stream>>>(Iq, (float*)Iq, n_nodes);
        pbe_reduce<<<grid_nodes, T, 0, stream>>>(V, S, (float*)Iq, sums_fb, n_nodes);
        pbe_finalize<<<1, 64, 0, stream>>>(sums_fb, (float*)d_out, 1.0f / (float)n_nodes);
    }
}